// Round 7
// baseline (764.458 us; speedup 1.0000x reference)
//
#include <hip/hip_runtime.h>

using half4   = __attribute__((ext_vector_type(4))) _Float16;
using half8   = __attribute__((ext_vector_type(8))) _Float16;
using floatx4 = __attribute__((ext_vector_type(4))) float;

namespace {
constexpr int S = 196, D = 512, C = 1006;
constexpr int CB     = 8;    // c per block; MFMA M-tile = 2s x 8c
constexpr int EBLK   = 256;  // e per block (et split: 2x tanh dup, buys grid=504 => 2 blocks/CU)
constexpr int BK     = 32;   // k-chunk = exactly 1 MFMA k-step
constexpr int NCHUNK = 16;   // D/BK
constexpr int TPB    = 512;  // 8 waves; wave = 32-wide e-slot (2 ej x 16)
constexpr int SROWS  = 8;    // s-rows per pass
constexpr int NPASS  = 25;   // 24x8 + 4-tail = 196
constexpr float KTANH = 2.885390082f;   // 2/ln2, folded into imgC staging
constexpr float LOG2E = 1.44269504f;    // folded into W: acc = log2e*feat

// r11 = r10 + two fixes:
//  (1) CORRECTNESS: the 16-row M-tile packs 2 s-rows x 8 c-rows; D-decode
//      m=quad*4+r means quad>>1 = s1. Threads quad and quad^2 accumulate
//      DISJOINT s-subsets of the SAME (c,e) outputs -> must be combined.
//      r10 had both write partial a/l (last-writer-wins => absmax 0.32).
//      Fix: __shfl_xor(.,32) combine (lane^32 flips the s1 bit), write quad<2.
//  (2) PERF: BK=32 rows stride 64B -> unswizzled b128 frag reads are 4-way
//      bank conflicts. XOR the 16B-pair index with (row>>1)&3 (pre-applied to
//      the W image in prep so the linear global_load_lds DMA is unchanged;
//      applied at the 8B-aligned ds_write for Tc).

__device__ __forceinline__ void gload16(const _Float16* g, _Float16* l) {
    // async global->LDS, 16B/lane; LDS dest = wave-uniform base + lane*16
    __builtin_amdgcn_global_load_lds(
        (const __attribute__((address_space(1))) unsigned int*)g,
        (__attribute__((address_space(3))) unsigned int*)l, 16, 0, 0);
}

__device__ __forceinline__ _Float16 tanh_ps(float y) {
    // y = (2/ln2)*x; tanh(x) = 1 - 2/(exp2(y)+1); saturates correctly (inf->1)
    float e = __builtin_amdgcn_exp2f(y);
    return (_Float16)(1.0f - 2.0f * __builtin_amdgcn_rcpf(e + 1.0f));
}

__device__ __forceinline__ half4 tanh4(floatx4 iv, floatx4 w) {
    half4 t;
    t[0] = tanh_ps(iv[0] * w[0]); t[1] = tanh_ps(iv[1] * w[1]);
    t[2] = tanh_ps(iv[2] * w[2]); t[3] = tanh_ps(iv[3] * w[3]);
    return t;
}

// fc3_w * log2e -> f16 image [chunk 16][e 512][k 32], 16B pairs XOR-swizzled by
// (e>>1)&3 so the per-block e-half DMAs LINEARLY and frag reads are conflict-free.
__global__ void prep_w32(const float* __restrict__ fw, _Float16* __restrict__ W32) {
    int id = blockIdx.x * blockDim.x + threadIdx.x;   // 32768 half8-segs
    int e = id >> 6, j = id & 63;                     // k = j*8
    const float* src = fw + (size_t)e * D + j * 8;
    floatx4 v0 = *(const floatx4*)src;
    floatx4 v1 = *(const floatx4*)(src + 4);
    half8 h;
    h[0] = (_Float16)(v0[0]*LOG2E); h[1] = (_Float16)(v0[1]*LOG2E);
    h[2] = (_Float16)(v0[2]*LOG2E); h[3] = (_Float16)(v0[3]*LOG2E);
    h[4] = (_Float16)(v1[0]*LOG2E); h[5] = (_Float16)(v1[1]*LOG2E);
    h[6] = (_Float16)(v1[2]*LOG2E); h[7] = (_Float16)(v1[3]*LOG2E);
    int pairSw = (j & 3) ^ ((e >> 1) & 3);            // swizzled 16B pair within chunk
    *(half8*)&W32[(size_t)(j >> 2) * 16384 + e * 32 + pairSw * 8] = h;
}

__global__ __launch_bounds__(TPB, 4) void semdec_mfma(
    const float* __restrict__ img, const float* __restrict__ word,
    const _Float16* __restrict__ W32, float* __restrict__ out)
{
    __shared__ __align__(16) _Float16 Wc[2][EBLK * BK];     // 2 x 16 KB
    __shared__ __align__(16) _Float16 Tc[2][4 * 16 * BK];   // 2 x 4 KB (4 sp-tiles of 16x32)
    __shared__ __align__(16) float    imgC[2][SROWS][BK];   // 2 x 1 KB, KTANH-prescaled
    // total 42 KB -> 2 blocks/CU (grid 504), VGPR<=128 via launch_bounds

    const int ct = blockIdx.x;            // 0..125
    const int b  = blockIdx.y;            // 0..1
    const int et = blockIdx.z;            // 0..1

    const int tid  = threadIdx.x;
    const int lane = tid & 63;
    const int wv   = tid >> 6;            // 0..7
    const int l15  = lane & 15;
    const int quad = lane >> 4;
    const int ySw  = (l15 >> 1) & 3;      // frag-read bank swizzle key (row = ..+l15)

    const int c0 = ct * CB;
    const int e0 = et * EBLK;

    // tanh-stage map: thread -> (spT = tid>>7, rowT = s1*8+ci, segT)
    const int spT  = tid >> 7;                        // s-pair tile 0..3
    const int s1T  = wv & 1;                          // row16>>3
    const int ciT  = lane >> 3;                       // 0..7 (c within tile)
    const int segT = lane & 7;                        // k slot of 4 halfs
    const int rowT = s1T * 8 + ciT;                   // 0..15
    // swizzled write offset (halfs): pair' = (segT>>1) ^ ((rowT>>1)&3), + lo*4
    const int tcOff = spT * 512 + rowT * 32 +
                      ((((segT >> 1) ^ ((rowT >> 1) & 3)) << 3) | ((segT & 1) << 2));
    int cgT = c0 + ciT; if (cgT > C - 1) cgT = C - 1; // clamp pad c-rows
    const float* wordT = word + (size_t)cgT * D + segT * 4;

    const float* imgB = img + (size_t)b * S * D;

    floatx4 acc[4][2];                    // [sp][ej] 32 VGPR
    floatx4 lacc[2], aacc[2];             // 16 VGPR softmax sums
    #pragma unroll
    for (int ej = 0; ej < 2; ++ej) {
        lacc[ej] = (floatx4){0.f,0.f,0.f,0.f};
        aacc[ej] = (floatx4){0.f,0.f,0.f,0.f};
    }

    // ---- prime: imgC for chunks 0,1; DMA W chunk0; word chain
    if (lane < 8) {   // each wave stages its own img row (s_local == wv)
        floatx4 v0 = *(const floatx4*)&imgB[(size_t)wv * D + lane * 4];
        floatx4 v1 = *(const floatx4*)&imgB[(size_t)wv * D + BK + lane * 4];
        *(floatx4*)&imgC[0][wv][lane * 4] = v0 * KTANH;
        *(floatx4*)&imgC[1][wv][lane * 4] = v1 * KTANH;
    }
    {   // DMA W chunk 0 -> Wc[0] (e-half region contiguous in the image)
        const _Float16* wg = W32 + (size_t)e0 * BK;
        int o = (wv * 2) * 512 + lane * 8;
        gload16(wg + o, &Wc[0][o]);
        gload16(wg + o + 512, &Wc[0][o + 512]);
    }
    floatx4 w0 = *(const floatx4*)(wordT);            // words chunk 0
    floatx4 wc = *(const floatx4*)(wordT + BK);       // words chunk 1
    __syncthreads();  // imgC visible; Wc[0] DMA drained
    {   // tanh chunk 0 -> Tc[0]
        floatx4 iv = *(const floatx4*)&imgC[0][wv][segT * 4];
        *(half4*)&Tc[0][tcOff] = tanh4(iv, w0);
    }

    for (int pr = 0; pr < NPASS; ++pr) {
        #pragma unroll
        for (int sp = 0; sp < 4; ++sp)
            #pragma unroll
            for (int ej = 0; ej < 2; ++ej)
                acc[sp][ej] = (floatx4){0.f,0.f,0.f,0.f};

        for (int kk = 0; kk < NCHUNK; ++kk) {
            const int p   = kk & 1;
            const int lin = pr * NCHUNK + kk;
            const bool last = (lin == NPASS * NCHUNK - 1);
            __syncthreads();  // Tc[p],Wc[p],imgC[p^1] visible; DMA drained; [p^1] readers done

            // --- DMA W chunk (kk+1)&15 -> Wc[p^1] (drains at next barrier)
            if (!last) {
                const _Float16* wg = W32 + (size_t)((kk + 1) & 15) * 16384 + (size_t)e0 * BK;
                int o = (wv * 2) * 512 + lane * 8;
                gload16(wg + o, &Wc[p ^ 1][o]);
                gload16(wg + o + 512, &Wc[p ^ 1][o + 512]);
            }

            // --- stage imgC for chunk lin+2 -> imgC[p] (read by tanh next chunk)
            if (!last && lane < 8) {
                const int sc = lin + 2;
                int srow = (sc >> 4) * SROWS + wv; if (srow > S - 1) srow = S - 1;
                floatx4 v = *(const floatx4*)&imgB[(size_t)srow * D + (sc & 15) * BK + lane * 4];
                *(floatx4*)&imgC[p][wv][lane * 4] = v * KTANH;
            }

            // --- word prefetch for chunk lin+2 (k-pattern cyclic over passes)
            floatx4 wn = *(const floatx4*)(wordT + ((kk + 2) & 15) * BK);

            // --- frag reads (XOR pair-swizzle: 2 accesses/bank = floor, conflict-free)
            half8 bf[2], af[4];
            #pragma unroll
            for (int ej = 0; ej < 2; ++ej)
                bf[ej] = *(const half8*)&Wc[p][(wv * 32 + ej * 16 + l15) * BK + ((quad ^ ySw) << 3)];
            #pragma unroll
            for (int sp = 0; sp < 4; ++sp)
                af[sp] = *(const half8*)&Tc[p][sp * 512 + l15 * 32 + ((quad ^ ySw) << 3)];

            // --- tanh chunk lin+1 -> Tc[p^1] (overlaps MFMA on separate pipes)
            if (!last) {
                floatx4 iv = *(const floatx4*)&imgC[p ^ 1][wv][segT * 4];
                *(half4*)&Tc[p ^ 1][tcOff] = tanh4(iv, wc);
                wc = wn;
            }

            // --- 8 MFMA (M = 2s x 8c, N = 32 e, K = 32)
            #pragma unroll
            for (int sp = 0; sp < 4; ++sp)
                #pragma unroll
                for (int ej = 0; ej < 2; ++ej)
                    acc[sp][ej] = __builtin_amdgcn_mfma_f32_16x16x32_f16(
                        af[sp], bf[ej], acc[sp][ej], 0, 0, 0);
        }

        // --- per-pass online softmax accumulate (acc = log2e*feat)
        const int s0 = pr * SROWS;
        #pragma unroll
        for (int sp = 0; sp < 4; ++sp) {
            const int sg_ = s0 + sp * 2 + (quad >> 1);   // D-row s1 = quad>>1
            if (sg_ < S) {
                #pragma unroll
                for (int ej = 0; ej < 2; ++ej) {
                    const int eg = e0 + wv * 32 + ej * 16 + l15;
                    float ie = imgB[(size_t)sg_ * D + eg];   // raw img, L2-hot
                    #pragma unroll
                    for (int r = 0; r < 4; ++r) {
                        float ev = __builtin_amdgcn_exp2f(acc[sp][ej][r]);
                        lacc[ej][r] += ev;
                        aacc[ej][r] += ie * ev;
                    }
                }
            }
        }
    }

    // --- combine the two s1-subsets: quad and quad^2 hold complementary s-halves
    //     of the SAME (c,e) outputs (lane^32 flips quad bit1 = s1). r10's missing step.
    #pragma unroll
    for (int ej = 0; ej < 2; ++ej)
        #pragma unroll
        for (int r = 0; r < 4; ++r) {
            float lv = lacc[ej][r], av = aacc[ej][r];
            lacc[ej][r] = lv + __shfl_xor(lv, 32);
            aacc[ej][r] = av + __shfl_xor(av, 32);
        }

    // --- writeout: quad<2 owns; c = c0 + quad*4 + r, e = e0 + wv*32 + ej*16 + l15
    if (quad < 2) {
        #pragma unroll
        for (int r = 0; r < 4; ++r) {
            const int cg = c0 + quad * 4 + r;
            if (cg < C) {
                #pragma unroll
                for (int ej = 0; ej < 2; ++ej) {
                    const int eg = e0 + wv * 32 + ej * 16 + l15;
                    out[((size_t)b * C + cg) * D + eg] = aacc[ej][r] / lacc[ej][r];
                }
            }
        }
    }
}

} // namespace

extern "C" void kernel_launch(void* const* d_in, const int* in_sizes, int n_in,
                              void* d_out, int out_size, void* d_ws, size_t ws_size,
                              hipStream_t stream) {
    const float* img  = (const float*)d_in[0];
    const float* word = (const float*)d_in[1];
    const float* fw   = (const float*)d_in[2];
    // d_in[3] = fc3_b: constant over softmax axis s -> cancels exactly.
    float* out = (float*)d_out;

    _Float16* W32 = (_Float16*)d_ws;     // 512 KB; only workspace use

    hipLaunchKernelGGL(prep_w32, dim3(128), dim3(256), 0, stream, fw, W32);
    hipLaunchKernelGGL(semdec_mfma, dim3(126, 2, 2), dim3(TPB), 0, stream,
                       img, word, W32, out);
}

// Round 8
// 706.013 us; speedup vs baseline: 1.0828x; 1.0828x over previous
//
#include <hip/hip_runtime.h>

using half8   = __attribute__((ext_vector_type(8))) _Float16;
using floatx4 = __attribute__((ext_vector_type(4))) float;

namespace {
constexpr int S = 196, D = 512, C = 1006;
constexpr int CB   = 16;    // block c-tile
constexpr int EBLK = 256;   // block e-tile (et split)
constexpr int BK   = 64;    // k-chunk (8 chunks/pass, 2 MFMA k-steps each)
constexpr int TPB  = 512;   // 8 waves = 4 e-slots (ew) x 2 s-groups (sg)
constexpr int RS   = 64;    // Tc row stride (halfs); 16B-seg XOR swizzle
constexpr int NPASS = 25;   // 24 x 8s + 1 x 4s = 196
constexpr float KTANH = 2.885390082f;   // 2/ln2 (folded into word at tanh time)
constexpr float LOG2E = 1.44269504f;    // folded into W: acc = log2e*feat

// r12 = r8 skeleton (256 blocks = 1/CU, 8 waves, et x sg split, local softmax,
// no atomics) with the two measured LDS/barrier cuts:
//  - Wc DELETED: bf frags from global W16 (L2-resident, 512 KB), register-
//    prefetched ONE CHUNK ahead (bfP/bfN) -> full-chunk latency cover.
//    (r9 failed with zero-distance prefetch at 2 waves/SIMD, not the path.)
//  - imgS DELETED: tanh inputs + epilogue ie read from global img (wave-
//    uniform rows -> 4 cache lines/inst, L1/L2-hot; r11 proved the ie variant).
//    Pipeline fully cyclic: tanh at chunk lin builds chunk lin+1 across pass
//    boundaries; ONE barrier per chunk, none at pass boundaries.
// Occupancy lesson (r5/r6/r11): per-thread state needs >128 unified regs ->
// 4 waves/SIMD always spills (VGPR=64/128 + GB-scale FETCH). Stay at (512,2).

__device__ __forceinline__ int sw_off(int row, int seg) {
    return row * RS + ((seg ^ (row & 7)) << 3);
}

__device__ __forceinline__ _Float16 tanh_ps(float y) {
    // y = (2/ln2)*x; tanh(x) = 1 - 2/(exp2(y)+1); saturates correctly
    float e = __builtin_amdgcn_exp2f(y);
    return (_Float16)(1.0f - 2.0f * __builtin_amdgcn_rcpf(e + 1.0f));
}

__device__ __forceinline__ half8 tanh8(floatx4 i0, floatx4 i1, floatx4 w0, floatx4 w1) {
    half8 t;
    t[0] = tanh_ps(i0[0] * w0[0]); t[1] = tanh_ps(i0[1] * w0[1]);
    t[2] = tanh_ps(i0[2] * w0[2]); t[3] = tanh_ps(i0[3] * w0[3]);
    t[4] = tanh_ps(i1[0] * w1[0]); t[5] = tanh_ps(i1[1] * w1[1]);
    t[6] = tanh_ps(i1[2] * w1[2]); t[7] = tanh_ps(i1[3] * w1[3]);
    return t;
}

// fc3_w * log2e -> plain row-major f16 image [e:512][k:512] (global reads
// don't bank-conflict; a quad's 4 lanes cover one aligned 64B line per row).
__global__ void prep_w16(const float* __restrict__ fw, _Float16* __restrict__ W16) {
    int id = blockIdx.x * blockDim.x + threadIdx.x;    // 32768 half8-segs
    int r  = id >> 6;          // e row
    int j  = id & 63;          // k seg of 8
    const float* src = fw + (size_t)r * D + j * 8;
    floatx4 v0 = *(const floatx4*)src;
    floatx4 v1 = *(const floatx4*)(src + 4);
    half8 h;
    h[0] = (_Float16)(v0[0] * LOG2E); h[1] = (_Float16)(v0[1] * LOG2E);
    h[2] = (_Float16)(v0[2] * LOG2E); h[3] = (_Float16)(v0[3] * LOG2E);
    h[4] = (_Float16)(v1[0] * LOG2E); h[5] = (_Float16)(v1[1] * LOG2E);
    h[6] = (_Float16)(v1[2] * LOG2E); h[7] = (_Float16)(v1[3] * LOG2E);
    *(half8*)&W16[(size_t)r * D + j * 8] = h;
}

__global__ __launch_bounds__(TPB, 2) void semdec_mfma(
    const float* __restrict__ img, const float* __restrict__ word,
    const _Float16* __restrict__ W16, float* __restrict__ out)
{
    __shared__ __align__(16) _Float16 Tc[2][8 * CB * RS];  // 2 x 16 KB
    __shared__ __align__(16) float red[256 * 33];          // 33 KB, stride-33
    // total ~65 KB; 1 block/CU by grid design (256 blocks)

    const int ct = blockIdx.x;           // 0..63
    const int b  = blockIdx.y;           // 0..1
    const int et = blockIdx.z;           // 0..1

    const int tid  = threadIdx.x;
    const int lane = tid & 63;
    const int wv   = tid >> 6;           // 0..7
    const int l15  = lane & 15;
    const int quad = lane >> 4;
    const int sg   = wv >> 2;            // s-group 0/1
    const int ew   = wv & 3;             // e-slot 0..3 (64-wide)

    const int c0 = ct * CB;
    const int e0 = et * EBLK;

    // tanh map: thread -> (sT2, ciT, segT); sl = it*4 + sT2 (wave-uniform rows)
    const int sT2  = tid >> 7;           // 0..3
    const int ciT  = (tid >> 3) & 15;
    const int segT = tid & 7;
    int cgT = c0 + ciT; if (cgT > C - 1) cgT = C - 1;   // clamp pad c-rows
    const float* wordT = word + (size_t)cgT * D + segT * 8;
    const float* imgB  = img + (size_t)b * S * D;

    // bf addressing: row = e0 + ew*64 + ej*16 + l15, col byte = quad*8 (+k2*32 +kk*64)
    const _Float16* wbase = W16 + (size_t)(e0 + ew * 64 + l15) * D + quad * 8;

    floatx4 lacc[4], aacc[4];
    #pragma unroll
    for (int ej = 0; ej < 4; ++ej) {
        lacc[ej] = (floatx4){0.f,0.f,0.f,0.f};
        aacc[ej] = (floatx4){0.f,0.f,0.f,0.f};
    }

    // ---- prologue: bfP = chunk0/k2=0 frags; tanh chunk 0 -> Tc[0]
    half8 bfP[4];
    #pragma unroll
    for (int ej = 0; ej < 4; ++ej)
        bfP[ej] = *(const half8*)(wbase + (size_t)ej * 16 * D);
    {
        floatx4 w0 = *(const floatx4*)(wordT);
        floatx4 w1 = *(const floatx4*)(wordT + 4);
        w0 *= KTANH; w1 *= KTANH;
        #pragma unroll
        for (int it = 0; it < 2; ++it) {
            const int sl = it * 4 + sT2;
            const float* ip = &imgB[(size_t)sl * D + segT * 8];
            floatx4 i0 = *(const floatx4*)ip;
            floatx4 i1 = *(const floatx4*)(ip + 4);
            *(half8*)&Tc[0][sw_off(sl * CB + ciT, segT)] = tanh8(i0, i1, w0, w1);
        }
    }

    for (int pr = 0; pr < NPASS; ++pr) {
        floatx4 acc[4][4];   // [si][ej] 64 AGPR
        #pragma unroll
        for (int si = 0; si < 4; ++si)
            #pragma unroll
            for (int ej = 0; ej < 4; ++ej)
                acc[si][ej] = (floatx4){0.f,0.f,0.f,0.f};

        #pragma unroll
        for (int kk = 0; kk < 8; ++kk) {
            const int p   = kk & 1;
            const int lin = pr * 8 + kk;
            __syncthreads();  // Tc[p] (written last chunk) visible; Tc[p^1] readers done

            // --- af frags (both k2) from Tc[p]; only LDS reads in the loop
            half8 af0[4], af1[4];
            #pragma unroll
            for (int si = 0; si < 4; ++si)
                af0[si] = *(const half8*)&Tc[p][sw_off((sg * 4 + si) * CB + l15, quad)];
            #pragma unroll
            for (int si = 0; si < 4; ++si)
                af1[si] = *(const half8*)&Tc[p][sw_off((sg * 4 + si) * CB + l15, 4 + quad)];

            // --- global issues: tanh inputs for chunk lin+1 (cyclic across passes)
            const int tl  = lin + 1;
            const int tkk = tl & 7;
            const int tp0 = (tl >> 3) * 8;
            floatx4 ti0[2], ti1[2];
            #pragma unroll
            for (int it = 0; it < 2; ++it) {
                int srow = tp0 + it * 4 + sT2; if (srow > S - 1) srow = S - 1;
                const float* ip = &imgB[(size_t)srow * D + tkk * 64 + segT * 8];
                ti0[it] = *(const floatx4*)ip;
                ti1[it] = *(const floatx4*)(ip + 4);
            }
            floatx4 w0 = *(const floatx4*)(wordT + tkk * 64);
            floatx4 w1 = *(const floatx4*)(wordT + tkk * 64 + 4);
            // --- bf k2=1 (this chunk; consumed after tanh) and k2=0 (next chunk)
            half8 bf1[4], bfN[4];
            #pragma unroll
            for (int ej = 0; ej < 4; ++ej)
                bf1[ej] = *(const half8*)(wbase + (size_t)ej * 16 * D + kk * 64 + 32);
            #pragma unroll
            for (int ej = 0; ej < 4; ++ej)
                bfN[ej] = *(const half8*)(wbase + (size_t)ej * 16 * D + ((kk + 1) & 7) * 64);

            // --- MFMA k2=0 (bfP prefetched a full chunk ago)
            #pragma unroll
            for (int si = 0; si < 4; ++si)
                #pragma unroll
                for (int ej = 0; ej < 4; ++ej)
                    acc[si][ej] = __builtin_amdgcn_mfma_f32_16x16x32_f16(
                        af0[si], bfP[ej], acc[si][ej], 0, 0, 0);

            // --- tanh chunk lin+1 -> Tc[p^1] (VALU/trans overlaps matrix pipe)
            w0 *= KTANH; w1 *= KTANH;
            #pragma unroll
            for (int it = 0; it < 2; ++it) {
                const int sl = it * 4 + sT2;
                *(half8*)&Tc[p ^ 1][sw_off(sl * CB + ciT, segT)] =
                    tanh8(ti0[it], ti1[it], w0, w1);
            }

            // --- MFMA k2=1 (bf1 issued ~full half-chunk ago)
            #pragma unroll
            for (int si = 0; si < 4; ++si)
                #pragma unroll
                for (int ej = 0; ej < 4; ++ej)
                    acc[si][ej] = __builtin_amdgcn_mfma_f32_16x16x32_f16(
                        af1[si], bf1[ej], acc[si][ej], 0, 0, 0);

            // --- rotate prefetch (full unroll -> pure register rename)
            #pragma unroll
            for (int ej = 0; ej < 4; ++ej)
                bfP[ej] = bfN[ej];
        }

        // --- pass epilogue: online softmax accumulate (acc = log2e*feat);
        //     ie from global img (wave-uniform row, 64B/inst, L2-hot)
        const int s0 = pr * 8;
        #pragma unroll
        for (int si = 0; si < 4; ++si) {
            const int sgrow = s0 + sg * 4 + si;
            if (sgrow < S) {
                #pragma unroll
                for (int ej = 0; ej < 4; ++ej) {
                    float ie = imgB[(size_t)sgrow * D + e0 + ew * 64 + ej * 16 + l15];
                    #pragma unroll
                    for (int r = 0; r < 4; ++r) {
                        float ev = __builtin_amdgcn_exp2f(acc[si][ej][r]);
                        lacc[ej][r] += ev;
                        aacc[ej][r] += ie * ev;
                    }
                }
            }
        }
    }

    // --- combine the two s-groups (stride-33: bank-clean) and write a/l
    __syncthreads();
    if (sg == 1) {
        const int base = (tid - 256) * 33;
        #pragma unroll
        for (int ej = 0; ej < 4; ++ej)
            #pragma unroll
            for (int r = 0; r < 4; ++r) {
                red[base + ej * 8 + r * 2]     = lacc[ej][r];
                red[base + ej * 8 + r * 2 + 1] = aacc[ej][r];
            }
    }
    __syncthreads();
    if (sg == 0) {
        const int base = tid * 33;
        #pragma unroll
        for (int r = 0; r < 4; ++r) {
            const int cg = c0 + quad * 4 + r;
            if (cg < C) {
                #pragma unroll
                for (int ej = 0; ej < 4; ++ej) {
                    float l = lacc[ej][r] + red[base + ej * 8 + r * 2];
                    float a = aacc[ej][r] + red[base + ej * 8 + r * 2 + 1];
                    const int eg = e0 + ew * 64 + ej * 16 + l15;
                    out[((size_t)b * C + cg) * D + eg] = a / l;
                }
            }
        }
    }
}

} // namespace

extern "C" void kernel_launch(void* const* d_in, const int* in_sizes, int n_in,
                              void* d_out, int out_size, void* d_ws, size_t ws_size,
                              hipStream_t stream) {
    const float* img  = (const float*)d_in[0];
    const float* word = (const float*)d_in[1];
    const float* fw   = (const float*)d_in[2];
    // d_in[3] = fc3_b: constant over softmax axis s -> cancels exactly.
    float* out = (float*)d_out;

    _Float16* W16 = (_Float16*)d_ws;     // 512 KB; only workspace use

    hipLaunchKernelGGL(prep_w16, dim3(128), dim3(256), 0, stream, fw, W16);
    hipLaunchKernelGGL(semdec_mfma, dim3(64, 2, 2), dim3(TPB), 0, stream,
                       img, word, W16, out);
}